// Round 4
// baseline (151.508 us; speedup 1.0000x reference)
//
#include <hip/hip_runtime.h>
#include <float.h>

// VQ-VAE vector quantizer, MI355X fp32 vector-ALU version, round 4.
// z: [32,64,32,32] f32, codebook: [1024,64] f32
// out (f32 flat): z_q [2097152] | loss [1] | indices-as-float [32768]
//
// Numerics contract (DO NOT CHANGE — bitwise-matches the numpy fp32 ref):
//  - code/pixel norms: numpy pairwise-sum tree over 64 rounded squares,
//    fp contract OFF
//  - dot: single k-ordered fma chain per (pixel, code)  (== BLAS sgemm
//    microkernel accumulation)
//  - score: fl(fl(zz+ee) - 2*dot); strict-< first-min, codes visited in
//    ascending-k order at every reduction level (wave, block, slice)
//
// Round-4 perf change: two-phase argmin to fix occupancy. Round 3 had
// 256 blocks on 256 CUs = 2 waves/SIMD; scalar/vector load waits idled the
// VALU (VALUBusy 44%). Phase 1 splits the code axis 4-ways: 2048 blocks x
// 256 thr, 1 px/lane, per-slice candidates to d_ws. Phase 2 reduces the 4
// candidates, writes idx/z_q/loss.

#define DIM       64
#define N_EMB     1024
#define N_PX      32768
#define LOSS_OFF  2097152
#define IDX_OFF   2097153
// loss = 1.25 * sum / 2^21  (exact fp32 constant)
#define LOSS_SCALE 5.9604644775390625e-07f

// numpy pairwise_sum over 64 elements of a^2, exact tree.
__device__ __forceinline__ float np_sumsq64(const float* a) {
    #pragma clang fp contract(off)
    float r[8];
    #pragma unroll
    for (int j = 0; j < 8; ++j) {
        float s = a[j] * a[j];
        #pragma unroll
        for (int m = 1; m < 8; ++m) {
            float p = a[j + 8 * m] * a[j + 8 * m];
            s = s + p;
        }
        r[j] = s;
    }
    return ((r[0] + r[1]) + (r[2] + r[3])) + ((r[4] + r[5]) + (r[6] + r[7]));
}

// Phase 1: grid 2048 = 512 px-groups x 4 code-slices; block 256 thr (4 waves).
// Lane owns 1 pixel; wave w owns codes [slice*256 + w*64, +64).
__global__ __launch_bounds__(256, 4)
void vq_argmin(const float* __restrict__ z, const float* __restrict__ cb,
               float* __restrict__ ws_val, int* __restrict__ ws_idx,
               float* __restrict__ out) {
    __shared__ float esq[256];
    __shared__ float cand_val[4 * 64];
    __shared__ int   cand_idx[4 * 64];

    const int tid  = threadIdx.x;
    const int lane = tid & 63;
    const int wave = __builtin_amdgcn_readfirstlane(tid >> 6);  // uniform
    const int g    = blockIdx.x >> 2;      // px-group 0..511 (64 px each)
    const int s    = blockIdx.x & 3;       // code slice 0..3 (256 codes each)
    const int n0   = g * 64;
    const int b    = n0 >> 10;
    const int hw0  = n0 & 1023;
    const size_t zbase = (size_t)b * 65536 + (size_t)hw0;   // z[b][c][hw]

    // ---- slice code norms -> LDS, numpy tree, no local array ----
    {
        #pragma clang fp contract(off)
        const int k = s * 256 + tid;
        const float* row = cb + (size_t)k * DIM;
        float r[8];
        #pragma unroll
        for (int j = 0; j < 8; ++j) {
            float acc = row[j] * row[j];
            #pragma unroll
            for (int m = 1; m < 8; ++m) {
                float p = row[j + 8 * m] * row[j + 8 * m];
                acc = acc + p;
            }
            r[j] = acc;
        }
        esq[tid] = ((r[0] + r[1]) + (r[2] + r[3])) + ((r[4] + r[5]) + (r[6] + r[7]));
    }

    // ---- this lane's pixel vector + its numpy-tree norm ----
    float vz[DIM];
    #pragma unroll
    for (int c = 0; c < DIM; ++c)
        vz[c] = z[zbase + (size_t)c * 1024 + lane];   // coalesced across lanes
    const float zz = np_sumsq64(vz);

    __syncthreads();

    // ---- argmin over this wave's 64-code slice, 4-code steps ----
    float best = FLT_MAX;
    int   bidx = 0;
    const int kb = s * 256 + wave * 64;
    for (int kk = 0; kk < 64; kk += 4) {
        const int k = kb + kk;
        const float* e = cb + (size_t)k * DIM;     // uniform -> s_load rows
        float d0 = 0.f, d1 = 0.f, d2 = 0.f, d3 = 0.f;
        #pragma unroll
        for (int c = 0; c < DIM; ++c) {
            const float v = vz[c];
            d0 = __builtin_fmaf(e[c],       v, d0);
            d1 = __builtin_fmaf(e[64 + c],  v, d1);
            d2 = __builtin_fmaf(e[128 + c], v, d2);
            d3 = __builtin_fmaf(e[192 + c], v, d3);
        }
        const int le = wave * 64 + kk;             // local esq index
        float s0, s1, s2, s3;
        {
            #pragma clang fp contract(off)
            const float p0 = zz + esq[le];
            const float p1 = zz + esq[le + 1];
            const float p2 = zz + esq[le + 2];
            const float p3 = zz + esq[le + 3];
            s0 = p0 - 2.0f * d0;
            s1 = p1 - 2.0f * d1;
            s2 = p2 - 2.0f * d2;
            s3 = p3 - 2.0f * d3;
        }
        if (s0 < best) { best = s0; bidx = k; }        // ascending k =>
        if (s1 < best) { best = s1; bidx = k + 1; }    // first-min kept
        if (s2 < best) { best = s2; bidx = k + 2; }
        if (s3 < best) { best = s3; bidx = k + 3; }
    }
    cand_val[wave * 64 + lane] = best;
    cand_idx[wave * 64 + lane] = bidx;
    __syncthreads();

    // ---- block reduce (4 waves, ascending w == ascending k) -> ws ----
    if (tid < 64) {
        float bv = cand_val[tid];
        int   bi = cand_idx[tid];
        #pragma unroll
        for (int w = 1; w < 4; ++w) {
            float v = cand_val[w * 64 + tid];
            int   i = cand_idx[w * 64 + tid];
            if (v < bv || (v == bv && i < bi)) { bv = v; bi = i; }
        }
        ws_val[s * N_PX + n0 + tid] = bv;
        ws_idx[s * N_PX + n0 + tid] = bi;
    }
    // zero the loss accumulator for phase 2 (stream-ordered before vq_out)
    if (blockIdx.x == 0 && tid == 0) out[LOSS_OFF] = 0.f;
}

// Phase 2: grid 512 x 256 thr; block = 64 px. Reduce 4 slice-candidates,
// write indices, z_q, and loss (one atomicAdd per block).
__global__ __launch_bounds__(256, 4)
void vq_out(const float* __restrict__ z, const float* __restrict__ cb,
            const float* __restrict__ ws_val, const int* __restrict__ ws_idx,
            float* __restrict__ out) {
    __shared__ int   fidx[64];
    __shared__ float lred[4];

    const int tid  = threadIdx.x;
    const int lane = tid & 63;
    const int wave = tid >> 6;
    const int n0   = blockIdx.x * 64;
    const int b    = n0 >> 10;
    const int hw0  = n0 & 1023;
    const size_t zbase = (size_t)b * 65536 + (size_t)hw0;

    if (tid < 64) {
        float bv = ws_val[n0 + tid];
        int   bi = ws_idx[n0 + tid];
        #pragma unroll
        for (int sl = 1; sl < 4; ++sl) {       // ascending slice == ascending k
            float v = ws_val[sl * N_PX + n0 + tid];
            int   i = ws_idx[sl * N_PX + n0 + tid];
            if (v < bv || (v == bv && i < bi)) { bv = v; bi = i; }
        }
        fidx[tid] = bi;
        out[IDX_OFF + n0 + tid] = (float)bi;
    }
    __syncthreads();

    const int px = tid & 63;
    const int cg = tid >> 6;      // 0..3 -> channels cg*16 .. cg*16+15
    const int mi = fidx[px];
    float lacc = 0.f;
    #pragma unroll
    for (int i = 0; i < 16; ++i) {
        const int c = cg * 16 + i;
        float q  = cb[mi * DIM + c];                    // L2-resident gather
        size_t go = zbase + (size_t)c * 1024 + px;
        float zv = z[go];                               // coalesced
        float d  = q - zv;
        lacc = __builtin_fmaf(d, d, lacc);
        out[go] = q;                                    // coalesced
    }
    #pragma unroll
    for (int off = 32; off > 0; off >>= 1)
        lacc += __shfl_down(lacc, off, 64);
    if (lane == 0) lred[wave] = lacc;
    __syncthreads();
    if (tid == 0) {
        float t = (lred[0] + lred[1]) + (lred[2] + lred[3]);
        atomicAdd(&out[LOSS_OFF], t * LOSS_SCALE);
    }
}

extern "C" void kernel_launch(void* const* d_in, const int* in_sizes, int n_in,
                              void* d_out, int out_size, void* d_ws, size_t ws_size,
                              hipStream_t stream) {
    const float* z  = (const float*)d_in[0];   // 2097152 f32
    const float* cb = (const float*)d_in[1];   // 65536 f32
    float* out = (float*)d_out;
    // workspace: 4 x 32768 candidate vals (512 KB) + 4 x 32768 idx (512 KB)
    float* ws_val = (float*)d_ws;
    int*   ws_idx = (int*)((char*)d_ws + 4u * N_PX * sizeof(float));

    vq_argmin<<<2048, 256, 0, stream>>>(z, cb, ws_val, ws_idx, out);
    vq_out<<<512, 256, 0, stream>>>(z, cb, ws_val, ws_idx, out);
}